// Round 4
// baseline (616.163 us; speedup 1.0000x reference)
//
#include <hip/hip_runtime.h>
#include <hip/hip_cooperative_groups.h>

namespace cg = cooperative_groups;

#define N_NODES 100000
#define D_FEAT  128
#define N_EDGES 1600000
#define EPSBN   1e-5f
#define SLOPE   0.01f

#define NBUCK   782          // ceil(100000 / 128) dst-buckets (128 nodes each)
#define PBLK    256          // partition blocks
#define CHUNK   6250         // edges per partition block (256*6250 = 1.6M exact)
#define PADMARG 640          // per-bucket extra csr capacity: 128*(self+3pad) + align
#define SETUPG  512          // setup grid (coop-resident safe: 2 blocks/CU)

typedef __attribute__((ext_vector_type(8))) short bf16x8;
typedef __attribute__((ext_vector_type(4))) float f32x4;
typedef unsigned short u16;
typedef unsigned int   u32;

__device__ __forceinline__ u16 f2bf(float f) {
    u32 x = __float_as_uint(f);
    u32 r = (x + 0x7fffu + ((x >> 16) & 1u)) >> 16;
    return (u16)r;
}
__device__ __forceinline__ float bf_lo(u32 w) { return __uint_as_float(w << 16); }
__device__ __forceinline__ float bf_hi(u32 w) { return __uint_as_float(w & 0xffff0000u); }

// ---------------- setup: ONE cooperative kernel ----------------
// P0: hist (blocks 0..255) + W-swizzle (256..271) + stats zero (272..275)
//     + Hb zero-rows (276)
// P1: per-bucket colscan over 256 chunk-blocks (grid-stride over buckets)
// P2: bscan of 782 bucket totals (block 0)
// P3: partition into packed 4B (src | (dst&127)<<20), bucket-contiguous
// P4: per-bucket padded-CSR build (self folded in, zero-row pads)

__global__ __launch_bounds__(256) void k_setup(const int* __restrict__ src,
                                               const int* __restrict__ dst,
                                               const float* __restrict__ W1,
                                               const float* __restrict__ W2,
                                               u16* __restrict__ wz1,
                                               u16* __restrict__ wz2,
                                               float* __restrict__ stats,
                                               u32* __restrict__ zlo,
                                               u32* __restrict__ zhi,
                                               int* __restrict__ hist,
                                               int* __restrict__ tot,
                                               int* __restrict__ bbase,
                                               u32* __restrict__ tmp,
                                               int4* __restrict__ meta,
                                               float* __restrict__ dinv,
                                               int* __restrict__ csr_src) {
    cg::grid_group grid = cg::this_grid();
    __shared__ int sh[NBUCK];
    __shared__ int sc[256];
    int tid = threadIdx.x, blk = blockIdx.x;

    // ---- P0 ----
    if (blk < PBLK) {
        for (int i = tid; i < NBUCK; i += 256) sh[i] = 0;
        __syncthreads();
        int e0 = blk * CHUNK;
        for (int e = e0 + tid; e < e0 + CHUNK; e += 256)
            atomicAdd(&sh[dst[e] >> 7], 1);
        __syncthreads();
        for (int i = tid; i < NBUCK; i += 256) hist[blk * NBUCK + i] = sh[i];
    } else if (blk < PBLK + 16) {
        int t = (blk - PBLK) * 256 + tid;      // 0..4095 over both W
        const float* W = (t < 2048) ? W1 : W2;
        u16* Wz = (t < 2048) ? wz1 : wz2;
        int tt = t & 2047;
        int lane = tt & 63, frag = tt >> 6;
        int nt = frag & 7, kc = frag >> 3;
        int n  = nt * 16 + (lane & 15);
        int kb = kc * 32 + (lane >> 4) * 8;
        u16 v[8];
#pragma unroll
        for (int j = 0; j < 8; ++j) v[j] = f2bf(W[(kb + j) * 128 + n]);
#pragma unroll
        for (int j = 0; j < 8; ++j) Wz[tt * 8 + j] = v[j];
    } else if (blk < PBLK + 20) {
        int t = (blk - PBLK - 16) * 256 + tid;
        if (t < 1024) stats[t] = 0.f;
    } else if (blk == PBLK + 20) {
        if (tid < 32) zlo[tid] = 0u;
        else if (tid < 64) zhi[tid - 32] = 0u;
    }
    grid.sync();

    // ---- P1: colscan ----
    for (int b = blk; b < NBUCK; b += SETUPG) {
        int c = hist[tid * NBUCK + b];
        sc[tid] = c;
        __syncthreads();
        for (int off = 1; off < 256; off <<= 1) {
            int add = (tid >= off) ? sc[tid - off] : 0;
            __syncthreads();
            sc[tid] += add;
            __syncthreads();
        }
        hist[tid * NBUCK + b] = sc[tid] - c;
        if (tid == 255) tot[b] = sc[255];
        __syncthreads();
    }
    grid.sync();

    // ---- P2: bscan (block 0) ----
    if (blk == 0) {
        int carry = 0;
        for (int base = 0; base < NBUCK; base += 256) {
            int idx = base + tid;
            int v = (idx < NBUCK) ? tot[idx] : 0;
            sc[tid] = v;
            __syncthreads();
            for (int off = 1; off < 256; off <<= 1) {
                int add = (tid >= off) ? sc[tid - off] : 0;
                __syncthreads();
                sc[tid] += add;
                __syncthreads();
            }
            if (idx < NBUCK) bbase[idx] = carry + sc[tid] - v;
            carry += sc[255];
            __syncthreads();
        }
        if (tid == 0) bbase[NBUCK] = N_EDGES;
    }
    grid.sync();

    // ---- P3: partition ----
    if (blk < PBLK) {
        for (int i = tid; i < NBUCK; i += 256)
            sh[i] = bbase[i] + hist[blk * NBUCK + i];
        __syncthreads();
        int e0 = blk * CHUNK;
        for (int e = e0 + tid; e < e0 + CHUNK; e += 256) {
            int s = src[e], d = dst[e];
            int slot = atomicAdd(&sh[d >> 7], 1);
            tmp[slot] = (u32)s | ((u32)(d & 127) << 20);
        }
    }
    grid.sync();

    // ---- P4: bucket build ----
    for (int b = blk; b < NBUCK; b += SETUPG) {
        int* lcnt = sh;
        int* scn  = sh + 128;
        int* lcur = sh + 256;
        int lo = bbase[b], hi = bbase[b + 1];
        int pbase = (lo & ~3) + b * PADMARG;
        if (tid < 128) lcnt[tid] = 0;
        __syncthreads();
        for (int e = lo + tid; e < hi; e += 256)
            atomicAdd(&lcnt[tmp[e] >> 20], 1);
        __syncthreads();
        int c  = (tid < 128) ? lcnt[tid] : 0;
        int c4 = (c + 4) & ~3;
        if (tid < 128) scn[tid] = c4;
        __syncthreads();
        for (int off = 1; off < 128; off <<= 1) {
            int add = (tid < 128 && tid >= off) ? scn[tid - off] : 0;
            __syncthreads();
            if (tid < 128) scn[tid] += add;
            __syncthreads();
        }
        if (tid < 128) {
            int node = (b << 7) + tid;
            int excl = pbase + scn[tid] - c4;
            lcur[tid] = excl;
            if (node < N_NODES) {
                float di = rsqrtf((float)(c + 1));
                dinv[node] = di;
                int4 m; m.x = excl >> 2; m.y = c4 >> 2; m.z = __float_as_int(di); m.w = 0;
                meta[node] = m;
                csr_src[excl + c] = node;           // self (Hb already *dinv)
                for (int k = c + 1; k < c4; ++k) csr_src[excl + k] = N_NODES;
            }
        }
        __syncthreads();
        for (int e = lo + tid; e < hi; e += 256) {
            u32 pk = tmp[e];
            int slot = atomicAdd(&lcur[pk >> 20], 1);
            csr_src[slot] = (int)(pk & 0xFFFFFu);
        }
        __syncthreads();
    }
}

// ---- GEMM: HbLo/HbHi[M x 64](bf16) = (act(A) @ W) * dinv[row], split-D halves
//   ABF16: A is packed bf16 (u32 pairs, 64/row); else f32.
//   FUSE:  act = leaky(A*scale+shift), scale/shift from BN sums in prologue

template <bool FUSE, bool ABF16>
__global__ __launch_bounds__(256) void k_gemm(const void* __restrict__ Ap,
                                              const u16* __restrict__ Wz,
                                              const float* __restrict__ sums,
                                              const float* __restrict__ sumsq,
                                              const float* __restrict__ gam,
                                              const float* __restrict__ bet,
                                              const float* __restrict__ dinv,
                                              u16* __restrict__ HbLo,
                                              u16* __restrict__ HbHi, int M) {
    __shared__ u16 wl[16384];  // 32 KB
    __shared__ float sLds[128], hLds[128];
    int tid = threadIdx.x;
    {
        const uint4* s4 = (const uint4*)Wz;
        uint4* d4 = (uint4*)wl;
        for (int i = tid; i < 2048; i += 256) d4[i] = s4[i];
    }
    if (FUSE && tid < 128) {
        float mean = sums[tid] * (1.f / N_NODES);
        float var  = sumsq[tid] * (1.f / N_NODES) - mean * mean;
        float rstd = rsqrtf(var + EPSBN);
        float sc = gam[tid] * rstd;
        sLds[tid] = sc;
        hLds[tid] = bet[tid] - mean * sc;
    }
    __syncthreads();
    int wave = tid >> 6, lane = tid & 63;
    long m0 = ((long)blockIdx.x * 4 + wave) * 16;
    if (m0 >= M) return;
    int mr = lane & 15, quad = lane >> 4;
    f32x4 acc[8] = {};
#pragma unroll
    for (int kc = 0; kc < 4; ++kc) {
        float av[8];
        if (ABF16) {
            const u32* arow = (const u32*)Ap + (size_t)(m0 + mr) * 64;
            uint4 aw = ((const uint4*)arow)[kc * 4 + quad];
            av[0] = bf_lo(aw.x); av[1] = bf_hi(aw.x);
            av[2] = bf_lo(aw.y); av[3] = bf_hi(aw.y);
            av[4] = bf_lo(aw.z); av[5] = bf_hi(aw.z);
            av[6] = bf_lo(aw.w); av[7] = bf_hi(aw.w);
        } else {
            const float* arow = (const float*)Ap + (size_t)(m0 + mr) * 128 + quad * 8;
            float4 a0 = *(const float4*)(arow + kc * 32);
            float4 a1 = *(const float4*)(arow + kc * 32 + 4);
            av[0] = a0.x; av[1] = a0.y; av[2] = a0.z; av[3] = a0.w;
            av[4] = a1.x; av[5] = a1.y; av[6] = a1.z; av[7] = a1.w;
        }
        if (FUSE) {
            int c = kc * 32 + quad * 8;
#pragma unroll
            for (int j = 0; j < 8; ++j) {
                float v = fmaf(av[j], sLds[c + j], hLds[c + j]);
                av[j] = v > 0.f ? v : v * SLOPE;
            }
        }
        bf16x8 af;
#pragma unroll
        for (int j = 0; j < 8; ++j) af[j] = (short)f2bf(av[j]);
        const u16* wb = wl + (kc * 4096 + lane * 8);
#pragma unroll
        for (int nt = 0; nt < 8; ++nt) {
            bf16x8 bf = *(const bf16x8*)(wb + nt * 512);
            acc[nt] = __builtin_amdgcn_mfma_f32_16x16x32_bf16(af, bf, acc[nt], 0, 0, 0);
        }
    }
    // C/D layout: col = nt*16 + (lane&15), row = quad*4 + r; split halves at col 64
    float dr[4];
#pragma unroll
    for (int r = 0; r < 4; ++r) dr[r] = dinv[m0 + quad * 4 + r];
    u16* hl = HbLo + (size_t)m0 * 64 + (lane & 15);
    u16* hh = HbHi + (size_t)m0 * 64 + (lane & 15);
#pragma unroll
    for (int nt = 0; nt < 8; ++nt) {
        u16* base = (nt < 4) ? (hl + nt * 16) : (hh + (nt - 4) * 16);
#pragma unroll
        for (int r = 0; r < 4; ++r)
            base[(size_t)(quad * 4 + r) * 64] = f2bf(acc[nt][r] * dr[r]);
    }
}

// ---------------- aggregation (split-D, two passes in one dispatch) ----------------
// One wave per (node, half). 8 groups of 8 lanes; per round each group reads one
// int4 of src indices (8 groups = 128B contiguous) and gathers 4 half-rows (128B).
// Blocks < 25000 do the lo half, >= 25000 the hi half -> 12.8 MB working set.

__device__ __forceinline__ void add8(float* acc, uint4 w) {
    acc[0] += bf_lo(w.x); acc[1] += bf_hi(w.x);
    acc[2] += bf_lo(w.y); acc[3] += bf_hi(w.y);
    acc[4] += bf_lo(w.z); acc[5] += bf_hi(w.z);
    acc[6] += bf_lo(w.w); acc[7] += bf_hi(w.w);
}

__global__ __launch_bounds__(256) void k_agg(const uint4* __restrict__ HbLo4,
                                             const uint4* __restrict__ HbHi4,
                                             const int4* __restrict__ meta,
                                             const int4* __restrict__ csr4,
                                             u32* __restrict__ AGGb) {
    int wave = threadIdx.x >> 6, lane = threadIdx.x & 63;
    int task = blockIdx.x * 4 + wave;        // 50000*4 = 200000 = 2*N_NODES
    int half = (task >= N_NODES) ? 1 : 0;
    int node = task - half * N_NODES;
    const uint4* H4 = half ? HbHi4 : HbLo4;
    int g = lane >> 3, f = lane & 7;
    int4 m = meta[node];                     // wave-uniform 16B broadcast
    int s4 = m.x, rn = m.y;
    float di = __int_as_float(m.z);
    float acc[8] = {0.f, 0.f, 0.f, 0.f, 0.f, 0.f, 0.f, 0.f};
    for (int r = g; r < rn; r += 8) {
        int4 idx = csr4[s4 + r];             // 8 lanes same addr; 8 groups = 128B
        uint4 a0 = H4[((size_t)idx.x << 3) + f];
        uint4 a1 = H4[((size_t)idx.y << 3) + f];
        uint4 a2 = H4[((size_t)idx.z << 3) + f];
        uint4 a3 = H4[((size_t)idx.w << 3) + f];
        add8(acc, a0); add8(acc, a1); add8(acc, a2); add8(acc, a3);
    }
#pragma unroll
    for (int i = 0; i < 8; ++i) {
        acc[i] += __shfl_xor(acc[i], 8);
        acc[i] += __shfl_xor(acc[i], 16);
        acc[i] += __shfl_xor(acc[i], 32);
    }
#pragma unroll
    for (int i = 0; i < 8; ++i) acc[i] *= di;
    if (g == 0) {                            // lanes 0..7 write 128B half-row
        u32 p0 = (u32)f2bf(acc[0]) | ((u32)f2bf(acc[1]) << 16);
        u32 p1 = (u32)f2bf(acc[2]) | ((u32)f2bf(acc[3]) << 16);
        u32 p2 = (u32)f2bf(acc[4]) | ((u32)f2bf(acc[5]) << 16);
        u32 p3 = (u32)f2bf(acc[6]) | ((u32)f2bf(acc[7]) << 16);
        uint4 o; o.x = p0; o.y = p1; o.z = p2; o.w = p3;
        ((uint4*)(AGGb + (size_t)node * 64))[half * 8 + f] = o;
    }
}

// ---------------- batch norm (bf16 AGG input) ----------------

__global__ void k_bnstats(const u32* __restrict__ AGGb, float* __restrict__ sums,
                          float* __restrict__ sumsq) {
    __shared__ float red[256];
    int col  = threadIdx.x & 127;
    int half = threadIdx.x >> 7;
    int odd  = col & 1, c2 = col >> 1;
    long r0 = (long)blockIdx.x * 200 + half;  // 500 blocks * 200 rows = 100000
    float s = 0.f, s2 = 0.f;
    for (int k = 0; k < 200; k += 2) {
        u32 w = AGGb[(r0 + k) * 64 + c2];
        float v = odd ? bf_hi(w) : bf_lo(w);
        s += v;
        s2 = fmaf(v, v, s2);
    }
    red[threadIdx.x] = s; __syncthreads();
    if (threadIdx.x < 128) atomicAdd(&sums[col], red[threadIdx.x] + red[threadIdx.x + 128]);
    __syncthreads();
    red[threadIdx.x] = s2; __syncthreads();
    if (threadIdx.x < 128) atomicAdd(&sumsq[col], red[threadIdx.x] + red[threadIdx.x + 128]);
}

// out = leaky(agg*scale + shift + x), f32 out; AGG bf16-packed, BN finalize inline.
__global__ __launch_bounds__(256) void k_ew2(const uint4* __restrict__ AGGb4,
                                             const float* __restrict__ sums,
                                             const float* __restrict__ sumsq,
                                             const float* __restrict__ gam,
                                             const float* __restrict__ bet,
                                             const float4* __restrict__ x4,
                                             float4* __restrict__ out4) {
    __shared__ float sLds[128], hLds[128];
    int tid = threadIdx.x;
    if (tid < 128) {
        float mean = sums[tid] * (1.f / N_NODES);
        float var  = sumsq[tid] * (1.f / N_NODES) - mean * mean;
        float rstd = rsqrtf(var + EPSBN);
        float sc = gam[tid] * rstd;
        sLds[tid] = sc;
        hLds[tid] = bet[tid] - mean * sc;
    }
    __syncthreads();
    long i = (long)blockIdx.x * 256 + tid;   // uint4 index; 6250*256 = 1.6M exact
    int c8 = ((int)i & 15) * 8;
    uint4 w = AGGb4[i];
    float4 xa = x4[2 * i], xb = x4[2 * i + 1];
    float4 oa, ob;
    float v;
    v = fmaf(bf_lo(w.x), sLds[c8+0], hLds[c8+0]) + xa.x; oa.x = v > 0.f ? v : v * SLOPE;
    v = fmaf(bf_hi(w.x), sLds[c8+1], hLds[c8+1]) + xa.y; oa.y = v > 0.f ? v : v * SLOPE;
    v = fmaf(bf_lo(w.y), sLds[c8+2], hLds[c8+2]) + xa.z; oa.z = v > 0.f ? v : v * SLOPE;
    v = fmaf(bf_hi(w.y), sLds[c8+3], hLds[c8+3]) + xa.w; oa.w = v > 0.f ? v : v * SLOPE;
    v = fmaf(bf_lo(w.z), sLds[c8+4], hLds[c8+4]) + xb.x; ob.x = v > 0.f ? v : v * SLOPE;
    v = fmaf(bf_hi(w.z), sLds[c8+5], hLds[c8+5]) + xb.y; ob.y = v > 0.f ? v : v * SLOPE;
    v = fmaf(bf_lo(w.w), sLds[c8+6], hLds[c8+6]) + xb.z; ob.z = v > 0.f ? v : v * SLOPE;
    v = fmaf(bf_hi(w.w), sLds[c8+7], hLds[c8+7]) + xb.w; ob.w = v > 0.f ? v : v * SLOPE;
    out4[2 * i]     = oa;
    out4[2 * i + 1] = ob;
}

// ---------------- launch ----------------

extern "C" void kernel_launch(void* const* d_in, const int* in_sizes, int n_in,
                              void* d_out, int out_size, void* d_ws, size_t ws_size,
                              hipStream_t stream) {
    const float* x   = (const float*)d_in[0];
    const int*   ei  = (const int*)d_in[1];
    const float* W1  = (const float*)d_in[2];
    const float* g1  = (const float*)d_in[4];
    const float* be1 = (const float*)d_in[5];
    const float* W2  = (const float*)d_in[6];
    const float* g2  = (const float*)d_in[8];
    const float* be2 = (const float*)d_in[9];
    const int* src = ei;
    const int* dst = ei + N_EDGES;

    float* out  = (float*)d_out;
    u16*   HbLo = (u16*)d_out;                             // 100001+ half-rows, 128B each
    u16*   HbHi = (u16*)d_out + (size_t)100096 * 64;       // second half array
    u32*   zlo  = (u32*)(HbLo + (size_t)N_NODES * 64);     // zero half-row lo
    u32*   zhi  = (u32*)(HbHi + (size_t)N_NODES * 64);     // zero half-row hi

    char* p = (char*)d_ws;
    u32*   aggb    = (u32*)p;   p += (size_t)N_NODES * 64 * 4;   // 25.6 MB bf16 AGG
    u32*   tmp     = (u32*)p;   p += (size_t)N_EDGES * 4;        // 6.4 MB packed edges
    int*   csr_src = (int*)p;   p += (size_t)2200000 * 4;        // 8.8 MB padded CSR
    int*   hist    = (int*)p;   p += (size_t)PBLK * NBUCK * 4;   // 0.8 MB
    int*   tot     = (int*)p;   p += 1024 * 4;
    int*   bbase   = (int*)p;   p += 1024 * 4;
    int4*  meta    = (int4*)p;  p += (size_t)100096 * 16;        // 1.6 MB
    float* dinv    = (float*)p; p += (size_t)100096 * 4;
    float* stats   = (float*)p; p += 1024 * 4;
    u16*   wz1     = (u16*)p;   p += 16384 * 2;
    u16*   wz2     = (u16*)p;   p += 16384 * 2;

    float* sums1 = stats,       *sq1 = stats + 128;
    float* sums2 = stats + 512, *sq2 = stats + 640;

    // one cooperative setup kernel: hist/swz/init -> colscan -> bscan -> part -> bucket
    {
        void* args[] = {(void*)&src, (void*)&dst, (void*)&W1, (void*)&W2,
                        (void*)&wz1, (void*)&wz2, (void*)&stats, (void*)&zlo,
                        (void*)&zhi, (void*)&hist, (void*)&tot, (void*)&bbase,
                        (void*)&tmp, (void*)&meta, (void*)&dinv, (void*)&csr_src};
        hipLaunchCooperativeKernel((const void*)k_setup, dim3(SETUPG), dim3(256),
                                   args, 0, stream);
    }

    // layer 1:  HbLo/Hi = (x@W1)*dinv,  AGG1(bf16) -> aggb
    k_gemm<false, false><<<1563, 256, 0, stream>>>(x, wz1, nullptr, nullptr, nullptr,
                                                   nullptr, dinv, HbLo, HbHi, N_NODES);
    k_agg<<<50000, 256, 0, stream>>>((const uint4*)HbLo, (const uint4*)HbHi,
                                     meta, (const int4*)csr_src, aggb);
    k_bnstats<<<500, 256, 0, stream>>>(aggb, sums1, sq1);

    // layer 2:  HbLo/Hi = (leaky(BN1(AGG1))@W2)*dinv;  AGG2(bf16) -> aggb
    k_gemm<true, true><<<1563, 256, 0, stream>>>(aggb, wz2, sums1, sq1, g1, be1,
                                                 dinv, HbLo, HbHi, N_NODES);
    k_agg<<<50000, 256, 0, stream>>>((const uint4*)HbLo, (const uint4*)HbHi,
                                     meta, (const int4*)csr_src, aggb);
    k_bnstats<<<500, 256, 0, stream>>>(aggb, sums2, sq2);

    // epilogue: BN2 finalize inline + residual + leaky
    k_ew2<<<6250, 256, 0, stream>>>((const uint4*)aggb, sums2, sq2, g2, be2,
                                    (const float4*)x, (float4*)out);
}

// Round 5
// 413.540 us; speedup vs baseline: 1.4900x; 1.4900x over previous
//
#include <hip/hip_runtime.h>

#define N_NODES 100000
#define D_FEAT  128
#define N_EDGES 1600000
#define EPSBN   1e-5f
#define SLOPE   0.01f

#define NBUCK   782          // ceil(100000 / 128) dst-buckets (128 nodes each)
#define NREG    8            // per-XCD write regions (blockIdx & 7)
#define SCAP    512          // tmp capacity per (region,bucket): Poisson(256), P(>512)~1e-43
#define CSTR    3584         // csr entries per bucket: sum c4 <= sum c + 512 <= 3584 (22-sigma)

typedef __attribute__((ext_vector_type(8))) short bf16x8;
typedef __attribute__((ext_vector_type(4))) float f32x4;
typedef unsigned short u16;
typedef unsigned int   u32;

__device__ __forceinline__ u16 f2bf(float f) {
    u32 x = __float_as_uint(f);
    u32 r = (x + 0x7fffu + ((x >> 16) & 1u)) >> 16;
    return (u16)r;
}
__device__ __forceinline__ float bf_lo(u32 w) { return __uint_as_float(w << 16); }
__device__ __forceinline__ float bf_hi(u32 w) { return __uint_as_float(w & 0xffff0000u); }

// ---------------- setup ----------------

// zero BN-stat scratch, zero-row of Hb (row N_NODES), init region cursors.
__global__ void k_init(float* stats, u32* zrow, int* bcur) {
    int i = blockIdx.x * 256 + threadIdx.x;   // 32*256 = 8192 threads
    if (i < 1024) stats[i] = 0.f;
    if (i < 64) zrow[i] = 0u;
    if (i < NREG * NBUCK) bcur[i] = i * SCAP;
}

// P1: scatter packed edges into per-(XCD-region, bucket) fixed segments of tmp.
// region = blockIdx&7 => consecutive slots of a segment are claimed by blocks of
// the same XCD => 64B lines assemble in that XCD's L2 (no cross-XCD line sharing).
__global__ __launch_bounds__(256) void k_part(const int* __restrict__ src,
                                              const int* __restrict__ dst,
                                              int* __restrict__ bcur,
                                              u32* __restrict__ tmp) {
    int i = blockIdx.x * 256 + threadIdx.x;   // 6250*256 = 1.6M exact
    int reg = blockIdx.x & (NREG - 1);
    int s = src[i], d = dst[i];
    int slot = atomicAdd(&bcur[reg * NBUCK + (d >> 7)], 1);
    tmp[slot] = (u32)s | ((u32)(d & 127) << 20);
}

// P2: one block per bucket. Count 128 node degrees in LDS over the 8 segments,
// LDS-scan PADDED counts (self + pad-to-4) -> padded CSR rows at fixed base:
//   row = [edges..., self, N_NODES-pads...]   (length multiple of 4, int4-aligned)
// meta[node] = { row_start_in_int4, rounds, bits(dinv), 0 }
__global__ __launch_bounds__(256) void k_bucket(const u32* __restrict__ tmp,
                                                const int* __restrict__ bcur,
                                                int4* __restrict__ meta,
                                                float* __restrict__ dinv,
                                                int* __restrict__ csr_src) {
    __shared__ int lcnt[128];
    __shared__ int sc[128];
    __shared__ int lcur[128];
    int tid = threadIdx.x, b = blockIdx.x;
    int pbase = b * CSTR;                       // int4-aligned (CSTR%4==0)
    if (tid < 128) lcnt[tid] = 0;
    __syncthreads();
    for (int seg = 0; seg < NREG; ++seg) {
        int lo = (seg * NBUCK + b) * SCAP;
        int hi = bcur[seg * NBUCK + b];
        for (int e = lo + tid; e < hi; e += 256)
            atomicAdd(&lcnt[tmp[e] >> 20], 1);
    }
    __syncthreads();
    int c  = (tid < 128) ? lcnt[tid] : 0;
    int c4 = (c + 4) & ~3;                      // edges + self, rounded up to 4
    if (tid < 128) sc[tid] = c4;
    __syncthreads();
    for (int off = 1; off < 128; off <<= 1) {
        int add = (tid < 128 && tid >= off) ? sc[tid - off] : 0;
        __syncthreads();
        if (tid < 128) sc[tid] += add;
        __syncthreads();
    }
    if (tid < 128) {
        int node = (b << 7) + tid;
        int excl = pbase + sc[tid] - c4;
        lcur[tid] = excl;
        if (node < N_NODES) {
            float di = rsqrtf((float)(c + 1));
            dinv[node] = di;
            int4 m; m.x = excl >> 2; m.y = c4 >> 2; m.z = __float_as_int(di); m.w = 0;
            meta[node] = m;
            csr_src[excl + c] = node;           // self contribution (Hb already *dinv)
            for (int k = c + 1; k < c4; ++k) csr_src[excl + k] = N_NODES;  // zero row
        }
    }
    __syncthreads();
    for (int seg = 0; seg < NREG; ++seg) {
        int lo = (seg * NBUCK + b) * SCAP;
        int hi = bcur[seg * NBUCK + b];
        for (int e = lo + tid; e < hi; e += 256) {
            u32 pk = tmp[e];
            int slot = atomicAdd(&lcur[pk >> 20], 1);
            csr_src[slot] = (int)(pk & 0xFFFFFu);
        }
    }
}

// Pre-swizzle W1+W2 (128x128 f32, row-major W[k][n]) into MFMA B-fragment order:
// frag t = (kc*8+nt)*64+lane holds 8 bf16: W[kc*32+(lane>>4)*8+j][nt*16+(lane&15)]
__global__ void k_swz(const float* __restrict__ W1, const float* __restrict__ W2,
                      u16* __restrict__ wz1, u16* __restrict__ wz2) {
    int t = blockIdx.x * 256 + threadIdx.x;  // 0..4095 over both W
    const float* W = (t < 2048) ? W1 : W2;
    u16* Wz = (t < 2048) ? wz1 : wz2;
    int tt = t & 2047;
    int lane = tt & 63, frag = tt >> 6;
    int nt = frag & 7, kc = frag >> 3;
    int n  = nt * 16 + (lane & 15);
    int kb = kc * 32 + (lane >> 4) * 8;
    u16 tmp[8];
#pragma unroll
    for (int j = 0; j < 8; ++j) tmp[j] = f2bf(W[(kb + j) * 128 + n]);
#pragma unroll
    for (int j = 0; j < 8; ++j) Wz[tt * 8 + j] = tmp[j];
}

// ---- GEMM: Hb[M x 128](bf16) = (act(A) @ W) * dinv[row]
//   ABF16: A is packed bf16 (u32 pairs, 64/row); else f32.
//   FUSE:  act = leaky(A*scale+shift), scale/shift computed from BN sums in prologue

template <bool FUSE, bool ABF16>
__global__ __launch_bounds__(256) void k_gemm(const void* __restrict__ Ap,
                                              const u16* __restrict__ Wz,
                                              const float* __restrict__ sums,
                                              const float* __restrict__ sumsq,
                                              const float* __restrict__ gam,
                                              const float* __restrict__ bet,
                                              const float* __restrict__ dinv,
                                              u16* __restrict__ Hb, int M) {
    __shared__ u16 wl[16384];  // 32 KB
    __shared__ float sLds[128], hLds[128];
    int tid = threadIdx.x;
    {
        const uint4* s4 = (const uint4*)Wz;
        uint4* d4 = (uint4*)wl;
        for (int i = tid; i < 2048; i += 256) d4[i] = s4[i];
    }
    if (FUSE && tid < 128) {
        float mean = sums[tid] * (1.f / N_NODES);
        float var  = sumsq[tid] * (1.f / N_NODES) - mean * mean;
        float rstd = rsqrtf(var + EPSBN);
        float sc = gam[tid] * rstd;
        sLds[tid] = sc;
        hLds[tid] = bet[tid] - mean * sc;
    }
    __syncthreads();
    int wave = tid >> 6, lane = tid & 63;
    long m0 = ((long)blockIdx.x * 4 + wave) * 16;
    if (m0 >= M) return;
    int mr = lane & 15, quad = lane >> 4;
    f32x4 acc[8] = {};
#pragma unroll
    for (int kc = 0; kc < 4; ++kc) {
        float av[8];
        if (ABF16) {
            const u32* arow = (const u32*)Ap + (size_t)(m0 + mr) * 64;
            uint4 aw = ((const uint4*)arow)[kc * 4 + quad];
            av[0] = bf_lo(aw.x); av[1] = bf_hi(aw.x);
            av[2] = bf_lo(aw.y); av[3] = bf_hi(aw.y);
            av[4] = bf_lo(aw.z); av[5] = bf_hi(aw.z);
            av[6] = bf_lo(aw.w); av[7] = bf_hi(aw.w);
        } else {
            const float* arow = (const float*)Ap + (size_t)(m0 + mr) * 128 + quad * 8;
            float4 a0 = *(const float4*)(arow + kc * 32);
            float4 a1 = *(const float4*)(arow + kc * 32 + 4);
            av[0] = a0.x; av[1] = a0.y; av[2] = a0.z; av[3] = a0.w;
            av[4] = a1.x; av[5] = a1.y; av[6] = a1.z; av[7] = a1.w;
        }
        if (FUSE) {
            int c = kc * 32 + quad * 8;
#pragma unroll
            for (int j = 0; j < 8; ++j) {
                float v = fmaf(av[j], sLds[c + j], hLds[c + j]);
                av[j] = v > 0.f ? v : v * SLOPE;
            }
        }
        bf16x8 af;
#pragma unroll
        for (int j = 0; j < 8; ++j) af[j] = (short)f2bf(av[j]);
        const u16* wb = wl + (kc * 4096 + lane * 8);  // fragment (kc,nt) at (kc*8+nt)*512
#pragma unroll
        for (int nt = 0; nt < 8; ++nt) {
            bf16x8 bf = *(const bf16x8*)(wb + nt * 512);
            acc[nt] = __builtin_amdgcn_mfma_f32_16x16x32_bf16(af, bf, acc[nt], 0, 0, 0);
        }
    }
    // C/D layout: col = lane&15, row = quad*4 + r ; scale row by dinv, store bf16
    float dr[4];
#pragma unroll
    for (int r = 0; r < 4; ++r) dr[r] = dinv[m0 + quad * 4 + r];
    u16* hb = Hb + (size_t)m0 * 128 + (lane & 15);
#pragma unroll
    for (int nt = 0; nt < 8; ++nt)
#pragma unroll
        for (int r = 0; r < 4; ++r)
            hb[(size_t)(quad * 4 + r) * 128 + nt * 16] = f2bf(acc[nt][r] * dr[r]);
}

// ---------------- aggregation ----------------
// One wave per node, 4 groups of 16 lanes. Padded CSR rows (multiple of 4,
// self folded in, zero-row pads): group g handles int4 slots r = g, g+4, ...
// Per round: one broadcast int4 index load + 4 row gathers + adds. No shfl,
// no tail masking, no weighted path.
// AGGb[d] = bf16( dinv[d] * sum_slots Hb[slot] )

__device__ __forceinline__ void add8(float* acc, uint4 w) {
    acc[0] += bf_lo(w.x); acc[1] += bf_hi(w.x);
    acc[2] += bf_lo(w.y); acc[3] += bf_hi(w.y);
    acc[4] += bf_lo(w.z); acc[5] += bf_hi(w.z);
    acc[6] += bf_lo(w.w); acc[7] += bf_hi(w.w);
}

__global__ __launch_bounds__(256) void k_agg(const uint4* __restrict__ Hb4,
                                             const int4* __restrict__ meta,
                                             const int4* __restrict__ csr4,
                                             u32* __restrict__ AGGb) {
    int wave = threadIdx.x >> 6, lane = threadIdx.x & 63;
    int node = blockIdx.x * 4 + wave;  // 25000*4 = 100000 exact
    int g = lane >> 4, f = lane & 15;
    int4 m = meta[node];               // wave-uniform 16B broadcast
    int s4 = m.x, rn = m.y;
    float di = __int_as_float(m.z);
    float acc[8] = {0.f, 0.f, 0.f, 0.f, 0.f, 0.f, 0.f, 0.f};
    for (int r = g; r < rn; r += 4) {
        int4 idx = csr4[s4 + r];       // 16 lanes same addr; 4 groups = 64B line
        uint4 a0 = Hb4[((size_t)idx.x << 4) + f];
        uint4 a1 = Hb4[((size_t)idx.y << 4) + f];
        uint4 a2 = Hb4[((size_t)idx.z << 4) + f];
        uint4 a3 = Hb4[((size_t)idx.w << 4) + f];
        add8(acc, a0); add8(acc, a1); add8(acc, a2); add8(acc, a3);
    }
#pragma unroll
    for (int i = 0; i < 8; ++i) {
        acc[i] += __shfl_xor(acc[i], 16);
        acc[i] += __shfl_xor(acc[i], 32);
    }
#pragma unroll
    for (int i = 0; i < 8; ++i) acc[i] *= di;
    if (g == 0) {                      // all groups hold the full sum; one writes
        u32 p0 = (u32)f2bf(acc[0]) | ((u32)f2bf(acc[1]) << 16);
        u32 p1 = (u32)f2bf(acc[2]) | ((u32)f2bf(acc[3]) << 16);
        u32 p2 = (u32)f2bf(acc[4]) | ((u32)f2bf(acc[5]) << 16);
        u32 p3 = (u32)f2bf(acc[6]) | ((u32)f2bf(acc[7]) << 16);
        uint4 o; o.x = p0; o.y = p1; o.z = p2; o.w = p3;
        ((uint4*)(AGGb + (size_t)node * 64))[f] = o;
    }
}

// ---------------- batch norm (bf16 AGG input) ----------------

__global__ void k_bnstats(const u32* __restrict__ AGGb, float* __restrict__ sums,
                          float* __restrict__ sumsq) {
    __shared__ float red[256];
    int col  = threadIdx.x & 127;
    int half = threadIdx.x >> 7;
    int odd  = col & 1, c2 = col >> 1;
    long r0 = (long)blockIdx.x * 200 + half;  // 500 blocks * 200 rows = 100000
    float s = 0.f, s2 = 0.f;
    for (int k = 0; k < 200; k += 2) {
        u32 w = AGGb[(r0 + k) * 64 + c2];
        float v = odd ? bf_hi(w) : bf_lo(w);
        s += v;
        s2 = fmaf(v, v, s2);
    }
    red[threadIdx.x] = s; __syncthreads();
    if (threadIdx.x < 128) atomicAdd(&sums[col], red[threadIdx.x] + red[threadIdx.x + 128]);
    __syncthreads();
    red[threadIdx.x] = s2; __syncthreads();
    if (threadIdx.x < 128) atomicAdd(&sumsq[col], red[threadIdx.x] + red[threadIdx.x + 128]);
}

// out = leaky(agg*scale + shift + x), f32 out; AGG bf16-packed, BN finalize inline.
// One thread = one uint4 of AGG (8 cols) + 2 float4 of x / out.
__global__ __launch_bounds__(256) void k_ew2(const uint4* __restrict__ AGGb4,
                                             const float* __restrict__ sums,
                                             const float* __restrict__ sumsq,
                                             const float* __restrict__ gam,
                                             const float* __restrict__ bet,
                                             const float4* __restrict__ x4,
                                             float4* __restrict__ out4) {
    __shared__ float sLds[128], hLds[128];
    int tid = threadIdx.x;
    if (tid < 128) {
        float mean = sums[tid] * (1.f / N_NODES);
        float var  = sumsq[tid] * (1.f / N_NODES) - mean * mean;
        float rstd = rsqrtf(var + EPSBN);
        float sc = gam[tid] * rstd;
        sLds[tid] = sc;
        hLds[tid] = bet[tid] - mean * sc;
    }
    __syncthreads();
    long i = (long)blockIdx.x * 256 + tid;   // uint4 index; 6250*256 = 1.6M exact
    int c8 = ((int)i & 15) * 8;
    uint4 w = AGGb4[i];
    float4 xa = x4[2 * i], xb = x4[2 * i + 1];
    float4 oa, ob;
    float v;
    v = fmaf(bf_lo(w.x), sLds[c8+0], hLds[c8+0]) + xa.x; oa.x = v > 0.f ? v : v * SLOPE;
    v = fmaf(bf_hi(w.x), sLds[c8+1], hLds[c8+1]) + xa.y; oa.y = v > 0.f ? v : v * SLOPE;
    v = fmaf(bf_lo(w.y), sLds[c8+2], hLds[c8+2]) + xa.z; oa.z = v > 0.f ? v : v * SLOPE;
    v = fmaf(bf_hi(w.y), sLds[c8+3], hLds[c8+3]) + xa.w; oa.w = v > 0.f ? v : v * SLOPE;
    v = fmaf(bf_lo(w.z), sLds[c8+4], hLds[c8+4]) + xb.x; ob.x = v > 0.f ? v : v * SLOPE;
    v = fmaf(bf_hi(w.z), sLds[c8+5], hLds[c8+5]) + xb.y; ob.y = v > 0.f ? v : v * SLOPE;
    v = fmaf(bf_lo(w.w), sLds[c8+6], hLds[c8+6]) + xb.z; ob.z = v > 0.f ? v : v * SLOPE;
    v = fmaf(bf_hi(w.w), sLds[c8+7], hLds[c8+7]) + xb.w; ob.w = v > 0.f ? v : v * SLOPE;
    out4[2 * i]     = oa;
    out4[2 * i + 1] = ob;
}

// ---------------- launch ----------------

extern "C" void kernel_launch(void* const* d_in, const int* in_sizes, int n_in,
                              void* d_out, int out_size, void* d_ws, size_t ws_size,
                              hipStream_t stream) {
    const float* x   = (const float*)d_in[0];
    const int*   ei  = (const int*)d_in[1];
    const float* W1  = (const float*)d_in[2];
    const float* g1  = (const float*)d_in[4];
    const float* be1 = (const float*)d_in[5];
    const float* W2  = (const float*)d_in[6];
    const float* g2  = (const float*)d_in[8];
    const float* be2 = (const float*)d_in[9];
    const int* src = ei;
    const int* dst = ei + N_EDGES;

    float* out = (float*)d_out;
    u16*   Hb  = (u16*)d_out;  // bf16 H (rows 0..N_NODES incl zero-row) lives in d_out

    char* p = (char*)d_ws;
    u32*   aggb    = (u32*)p;   p += (size_t)N_NODES * 64 * 4;   // 25.6 MB bf16 AGG
    u32*   tmp     = aggb;      // tmp (NREG*NBUCK*SCAP*4 = 12.8 MB) overlays aggb:
                                // dead before first k_agg write
    int*   csr_src = (int*)p;   p += (size_t)NBUCK * CSTR * 4;   // 11.2 MB padded CSR
    int*   bcur    = (int*)p;   p += (size_t)NREG * NBUCK * 4;   // 25 KB cursors
    int4*  meta    = (int4*)p;  p += (size_t)100096 * 16;        // 1.6 MB
    float* dinv    = (float*)p; p += (size_t)100096 * 4;
    float* stats   = (float*)p; p += 1024 * 4;
    u16*   wz1     = (u16*)p;   p += 16384 * 2;
    u16*   wz2     = (u16*)p;   p += 16384 * 2;

    float* sums1 = stats,       *sq1 = stats + 128;
    float* sums2 = stats + 512, *sq2 = stats + 640;

    // graph setup: cursor init -> XCD-region scatter -> per-bucket padded-CSR build
    k_init<<<32, 256, 0, stream>>>(stats, (u32*)Hb + (size_t)N_NODES * 64, bcur);
    k_part<<<6250, 256, 0, stream>>>(src, dst, bcur, tmp);
    k_bucket<<<NBUCK, 256, 0, stream>>>(tmp, bcur, meta, dinv, csr_src);
    k_swz<<<16, 256, 0, stream>>>(W1, W2, wz1, wz2);

    // layer 1:  Hb1 = (x@W1)*dinv -> d_out (bf16),  AGG1(bf16) -> aggb
    k_gemm<false, false><<<1563, 256, 0, stream>>>(x, wz1, nullptr, nullptr, nullptr,
                                                   nullptr, dinv, Hb, N_NODES);
    k_agg<<<25000, 256, 0, stream>>>((const uint4*)Hb, meta, (const int4*)csr_src, aggb);
    k_bnstats<<<500, 256, 0, stream>>>(aggb, sums1, sq1);

    // layer 2:  Hb2 = (leaky(BN1(AGG1))@W2)*dinv -> d_out;  AGG2(bf16) -> aggb
    k_gemm<true, true><<<1563, 256, 0, stream>>>(aggb, wz2, sums1, sq1, g1, be1,
                                                 dinv, Hb, N_NODES);
    k_agg<<<25000, 256, 0, stream>>>((const uint4*)Hb, meta, (const int4*)csr_src, aggb);
    k_bnstats<<<500, 256, 0, stream>>>(aggb, sums2, sq2);

    // epilogue: BN2 finalize inline + residual + leaky
    k_ew2<<<6250, 256, 0, stream>>>((const uint4*)aggb, sums2, sq2, g2, be2,
                                    (const float4*)x, (float4*)out);
}